// Round 3
// baseline (32924.963 us; speedup 1.0000x reference)
//
#include <hip/hip_runtime.h>

#define HID 51
#define TLEN 1024
#define NB 4            // batch elements per block
#define NTH 320         // 4 gate waves (204 gate lanes) + 1 projection wave

__device__ __forceinline__ float frcp(float v) { return __builtin_amdgcn_rcpf(v); }
__device__ __forceinline__ float sigm(float v) { return frcp(1.0f + __expf(-v)); }

__global__ __launch_bounds__(NTH, 2)
void lstm2_kernel(const float* __restrict__ x,
                  const float* __restrict__ W_ih0, const float* __restrict__ W_hh0,
                  const float* __restrict__ b_ih0, const float* __restrict__ b_hh0,
                  const float* __restrict__ W_ih1, const float* __restrict__ W_hh1,
                  const float* __restrict__ b_ih1, const float* __restrict__ b_hh1,
                  const float* __restrict__ W_lin, const float* __restrict__ b_lin,
                  float* __restrict__ out)
{
    const int tid = threadIdx.x;
    const int j   = tid >> 2;       // hidden index 0..50 (gate lanes)
    const int r   = tid & 3;        // gate role: 0=i 1=f 2=g 3=o
    const bool is_gate = (tid < 4 * HID);   // lanes 0..203 (waves 0..3)
    const bool is_proj = (tid >= 256);      // wave 4

    __shared__ __align__(16) float H0[2][NB][52];   // ping-pong x batch x hidden(+pad)
    __shared__ __align__(16) float H1[2][NB][52];
    __shared__ __align__(16) float XS[NB][TLEN];

    // zero-init H (pads stay 0 forever; uninit LDS could be NaN)
    for (int i = tid; i < 2 * NB * 52; i += NTH) {
        (&H0[0][0][0])[i] = 0.f;
        (&H1[0][0][0])[i] = 0.f;
    }
    // stage x for the 4 batch rows (contiguous in global memory)
    const size_t bb = (size_t)blockIdx.x * NB;
    {
        const float4* xsrc = reinterpret_cast<const float4*>(x + bb * TLEN);
        float4* xdst = reinterpret_cast<float4*>(&XS[0][0]);
        for (int i = tid; i < NB * TLEN / 4; i += NTH) xdst[i] = xsrc[i];
    }

    // per-lane persistent weights: row (r*51+j) of each matrix, padded to 52
    float w0[52], wi1[52], wh1[52];
    float bias0 = 0.f, bias1 = 0.f, wih0 = 0.f;
    const int grow = r * HID + j;
    if (is_gate) {
        #pragma unroll
        for (int k = 0; k < HID; ++k) {
            w0[k]  = W_hh0[grow * HID + k];
            wi1[k] = W_ih1[grow * HID + k];
            wh1[k] = W_hh1[grow * HID + k];
        }
        bias0 = b_ih0[grow] + b_hh0[grow];
        bias1 = b_ih1[grow] + b_hh1[grow];
        wih0  = W_ih0[grow];
    } else {
        #pragma unroll
        for (int k = 0; k < HID; ++k) { w0[k] = 0.f; wi1[k] = 0.f; wh1[k] = 0.f; }
    }
    w0[51] = 0.f; wi1[51] = 0.f; wh1[51] = 0.f;   // pad element contributes 0

    const float am = (r == 2) ? 2.f : 1.f;    // tanh(a) = 2*sigm(2a) - 1 for g-gate
    const float ad = (r == 2) ? -1.f : 0.f;
    const float blin = b_lin[0];
    float wlin = 0.f;
    if (is_proj) {
        const int jj = tid - 256;
        wlin = (jj < HID) ? W_lin[jj] : 0.f;
    }

    float c0[NB] = {0.f, 0.f, 0.f, 0.f};
    float c1[NB] = {0.f, 0.f, 0.f, 0.f};
    __syncthreads();

    for (int t = 0; t < TLEN; ++t) {
        const int p = t & 1;

        if (is_proj) {
            // projection of h1(t-1) -> out[*, t-1]; overlaps gate waves' phase A
            if (t > 0) {
                const int jj = tid - 256;
                float pr[NB];
                #pragma unroll
                for (int nb = 0; nb < NB; ++nb)
                    pr[nb] = (jj < HID) ? H1[p][nb][jj] * wlin : 0.f;
                #pragma unroll
                for (int s = 1; s < 64; s <<= 1) {
                    #pragma unroll
                    for (int nb = 0; nb < NB; ++nb) pr[nb] += __shfl_xor(pr[nb], s, 64);
                }
                if (jj == 0) {
                    #pragma unroll
                    for (int nb = 0; nb < NB; ++nb)
                        out[(bb + nb) * TLEN + (t - 1)] = pr[nb] + blin;
                }
            }
        } else if (is_gate) {
            // ---------- phase A : layer-0 gates for 4 batch elems ----------
            float acc[NB];
            #pragma unroll
            for (int nb = 0; nb < NB; ++nb) acc[nb] = fmaf(XS[nb][t], wih0, bias0);
            #pragma unroll
            for (int q = 0; q < 13; ++q) {
                #pragma unroll
                for (int nb = 0; nb < NB; ++nb) {
                    float4 hv = *reinterpret_cast<const float4*>(&H0[p][nb][4 * q]);
                    acc[nb] = fmaf(hv.x, w0[4*q+0], acc[nb]);
                    acc[nb] = fmaf(hv.y, w0[4*q+1], acc[nb]);
                    acc[nb] = fmaf(hv.z, w0[4*q+2], acc[nb]);
                    acc[nb] = fmaf(hv.w, w0[4*q+3], acc[nb]);
                }
            }
            #pragma unroll
            for (int nb = 0; nb < NB; ++nb) {
                float act = fmaf(am, sigm(am * acc[nb]), ad);
                float x1 = __shfl_xor(act, 1, 64);
                float x2 = __shfl_xor(act, 2, 64);
                float x3 = __shfl_xor(act, 3, 64);
                float gi = (r==0)?act : (r==1)?x1  : (r==2)?x2  : x3;
                float gf = (r==0)?x1  : (r==1)?act : (r==2)?x3  : x2;
                float gg = (r==0)?x2  : (r==1)?x3  : (r==2)?act : x1;
                float go = (r==0)?x3  : (r==1)?x2  : (r==2)?x1  : act;
                c0[nb] = fmaf(gf, c0[nb], gi * gg);
                float th = fmaf(2.f, sigm(2.f * c0[nb]), -1.f);
                if (r == 0) H0[1 - p][nb][j] = go * th;
            }
        }
        __syncthreads();   // #1: h0(t) visible

        if (is_gate) {
            // ---------- phase B : layer-1 gates for 4 batch elems ----------
            float acc[NB];
            #pragma unroll
            for (int nb = 0; nb < NB; ++nb) acc[nb] = bias1;
            #pragma unroll
            for (int q = 0; q < 13; ++q) {
                #pragma unroll
                for (int nb = 0; nb < NB; ++nb) {
                    float4 hv = *reinterpret_cast<const float4*>(&H0[1 - p][nb][4 * q]);
                    float4 gv = *reinterpret_cast<const float4*>(&H1[p][nb][4 * q]);
                    acc[nb] = fmaf(hv.x, wi1[4*q+0], acc[nb]);
                    acc[nb] = fmaf(hv.y, wi1[4*q+1], acc[nb]);
                    acc[nb] = fmaf(hv.z, wi1[4*q+2], acc[nb]);
                    acc[nb] = fmaf(hv.w, wi1[4*q+3], acc[nb]);
                    acc[nb] = fmaf(gv.x, wh1[4*q+0], acc[nb]);
                    acc[nb] = fmaf(gv.y, wh1[4*q+1], acc[nb]);
                    acc[nb] = fmaf(gv.z, wh1[4*q+2], acc[nb]);
                    acc[nb] = fmaf(gv.w, wh1[4*q+3], acc[nb]);
                }
            }
            #pragma unroll
            for (int nb = 0; nb < NB; ++nb) {
                float act = fmaf(am, sigm(am * acc[nb]), ad);
                float x1 = __shfl_xor(act, 1, 64);
                float x2 = __shfl_xor(act, 2, 64);
                float x3 = __shfl_xor(act, 3, 64);
                float gi = (r==0)?act : (r==1)?x1  : (r==2)?x2  : x3;
                float gf = (r==0)?x1  : (r==1)?act : (r==2)?x3  : x2;
                float gg = (r==0)?x2  : (r==1)?x3  : (r==2)?act : x1;
                float go = (r==0)?x3  : (r==1)?x2  : (r==2)?x1  : act;
                c1[nb] = fmaf(gf, c1[nb], gi * gg);
                float th = fmaf(2.f, sigm(2.f * c1[nb]), -1.f);
                if (r == 0) H1[1 - p][nb][j] = go * th;
            }
        }
        __syncthreads();   // #2: h1(t) visible (consumed by proj next iter / B next iter)
    }

    // final projection: out[*, 1023] from H1[(TLEN)&1 == 0]
    if (is_proj) {
        const int jj = tid - 256;
        float pr[NB];
        #pragma unroll
        for (int nb = 0; nb < NB; ++nb)
            pr[nb] = (jj < HID) ? H1[0][nb][jj] * wlin : 0.f;
        #pragma unroll
        for (int s = 1; s < 64; s <<= 1) {
            #pragma unroll
            for (int nb = 0; nb < NB; ++nb) pr[nb] += __shfl_xor(pr[nb], s, 64);
        }
        if (jj == 0) {
            #pragma unroll
            for (int nb = 0; nb < NB; ++nb)
                out[(bb + nb) * TLEN + (TLEN - 1)] = pr[nb] + blin;
        }
    }
}

extern "C" void kernel_launch(void* const* d_in, const int* in_sizes, int n_in,
                              void* d_out, int out_size, void* d_ws, size_t ws_size,
                              hipStream_t stream) {
    const float* x     = (const float*)d_in[0];
    const float* W_ih0 = (const float*)d_in[1];
    const float* W_hh0 = (const float*)d_in[2];
    const float* b_ih0 = (const float*)d_in[3];
    const float* b_hh0 = (const float*)d_in[4];
    const float* W_ih1 = (const float*)d_in[5];
    const float* W_hh1 = (const float*)d_in[6];
    const float* b_ih1 = (const float*)d_in[7];
    const float* b_hh1 = (const float*)d_in[8];
    const float* W_lin = (const float*)d_in[9];
    const float* b_lin = (const float*)d_in[10];
    float* out = (float*)d_out;

    const int B = in_sizes[0] / TLEN;
    lstm2_kernel<<<dim3(B / NB), dim3(NTH), 0, stream>>>(
        x, W_ih0, W_hh0, b_ih0, b_hh0, W_ih1, W_hh1, b_ih1, b_hh1, W_lin, b_lin, out);
}

// Round 4
// 3024.762 us; speedup vs baseline: 10.8851x; 10.8851x over previous
//
#include <hip/hip_runtime.h>

#define HID 51
#define TLEN 1024
#define NTH 448          // 7 waves; unit-quad layout: tid = 8*j + 4*h + r

__device__ __forceinline__ float frcp(float v) { return __builtin_amdgcn_rcpf(v); }
__device__ __forceinline__ float sigm(float v) { return frcp(1.0f + __expf(-v)); }

__global__ __launch_bounds__(NTH, 2)   // 2 waves/EU min -> 2 blocks/CU, 128-VGPR cap (no spill)
void lstm2_kernel(const float* __restrict__ x,
                  const float* __restrict__ W_ih0, const float* __restrict__ W_hh0,
                  const float* __restrict__ b_ih0, const float* __restrict__ b_hh0,
                  const float* __restrict__ W_ih1, const float* __restrict__ W_hh1,
                  const float* __restrict__ b_ih1, const float* __restrict__ b_hh1,
                  const float* __restrict__ W_lin, const float* __restrict__ b_lin,
                  float* __restrict__ out)
{
    const int b   = blockIdx.x;
    const int tid = threadIdx.x;
    const int j   = tid >> 3;          // hidden unit 0..55 (51..55 are pad units)
    const int r   = tid & 3;           // gate role: 0=i 1=f 2=g 3=o
    const int h   = (tid >> 2) & 1;    // dot-product half
    const bool valid = (j < HID);

    // h-vector slots: col<26 -> slot=col ; col in [26,51] -> slot=col+2.
    // Pad units write slots 53..57; every slot >= 53 is multiplied by a zero
    // weight on the read side, so pad writes are harmless. [2][64] per buffer.
    __shared__ __align__(16) float H0[2][64];
    __shared__ __align__(16) float H1[2][64];
    __shared__ float WS[8];
    __shared__ __align__(16) float XS[TLEN];

    if (tid < 128) { (&H0[0][0])[tid] = 0.f; (&H1[0][0])[tid] = 0.f; }
    if (tid < 8)  WS[tid] = 0.f;
    {
        const float4* xsrc = reinterpret_cast<const float4*>(x + (size_t)b * TLEN);
        float4* xdst = reinterpret_cast<float4*>(&XS[0]);
        if (tid < TLEN / 4) xdst[tid] = xsrc[tid];
    }

    // per-lane weights: half h of row (r*51+j) of W_hh0 / W_ih1 / W_hh1 (26 each)
    float w0[26], wi1[26], wh1[26];
    float bias0 = 0.f, bias1 = 0.f, wih0 = 0.f, wlinj = 0.f;
    const int grow = r * HID + j;
    #pragma unroll
    for (int k = 0; k < 26; ++k) {
        const int col = 26 * h + k;
        const bool v = valid && (col < HID);
        w0[k]  = v ? W_hh0[grow * HID + col] : 0.f;
        wi1[k] = v ? W_ih1[grow * HID + col] : 0.f;
        wh1[k] = v ? W_hh1[grow * HID + col] : 0.f;
    }
    if (valid && h == 0) {
        bias0 = b_ih0[grow] + b_hh0[grow];
        bias1 = b_ih1[grow] + b_hh1[grow];
        wih0  = W_ih0[grow];
        if (r == 0) wlinj = W_lin[j];
    }
    const float blin = b_lin[0];
    const float am = (r == 2) ? 2.f : 1.f;     // tanh(a) = 2*sigm(2a) - 1 for g-gate
    const float ad = (r == 2) ? -1.f : 0.f;
    const int   slotj = j + ((j >= 26) ? 2 : 0);
    const int   hb    = 28 * h;

    float c0 = 0.f, c1 = 0.f;
    float* orow = out + (size_t)b * TLEN;
    __syncthreads();

    for (int t = 0; t < TLEN; ++t) {
        const int p = t & 1;

        // ---------- phase A : layer-0 (all 448 lanes, branch-free) ----------
        {
            const float* hp = &H0[p][hb];
            float a0 = fmaf(XS[t], wih0, bias0);   // h==1 / pad lanes: 0*x+0
            float a1 = 0.f;
            #pragma unroll
            for (int q = 0; q < 3; ++q) {
                float4 va = *reinterpret_cast<const float4*>(hp + 8 * q);
                float4 vb = *reinterpret_cast<const float4*>(hp + 8 * q + 4);
                a0 = fmaf(va.x, w0[8*q+0], a0); a0 = fmaf(va.y, w0[8*q+1], a0);
                a0 = fmaf(va.z, w0[8*q+2], a0); a0 = fmaf(va.w, w0[8*q+3], a0);
                a1 = fmaf(vb.x, w0[8*q+4], a1); a1 = fmaf(vb.y, w0[8*q+5], a1);
                a1 = fmaf(vb.z, w0[8*q+6], a1); a1 = fmaf(vb.w, w0[8*q+7], a1);
            }
            float2 tl = *reinterpret_cast<const float2*>(hp + 24);
            a0 = fmaf(tl.x, w0[24], a0);
            a1 = fmaf(tl.y, w0[25], a1);
            float acc = a0 + a1;
            acc += __shfl_xor(acc, 4, 64);                   // combine halves
            float act = fmaf(am, sigm(am * acc), ad);        // gate activation
            float x1 = __shfl_xor(act, 1, 64);
            float x2 = __shfl_xor(act, 2, 64);
            float x3 = __shfl_xor(act, 3, 64);
            float gi = (r==0)?act : (r==1)?x1  : (r==2)?x2  : x3;
            float gf = (r==0)?x1  : (r==1)?act : (r==2)?x3  : x2;
            float gg = (r==0)?x2  : (r==1)?x3  : (r==2)?act : x1;
            float go = (r==0)?x3  : (r==1)?x2  : (r==2)?x1  : act;
            c0 = fmaf(gf, c0, gi * gg);
            float th = fmaf(2.f, sigm(2.f * c0), -1.f);      // tanh(c0)
            if ((tid & 7) == 0) H0[1 - p][slotj] = go * th;
        }
        __syncthreads();   // #1: h0(t) visible

        // ---------- phase B : layer-1 + projection ----------
        float part;
        {
            const float* h0n = &H0[1 - p][hb];
            const float* h1p = &H1[p][hb];
            float aA0 = bias1;                     // 0 for h==1 / pad lanes
            float aA1 = 0.f, aB0 = 0.f, aB1 = 0.f;
            #pragma unroll
            for (int q = 0; q < 3; ++q) {
                float4 va = *reinterpret_cast<const float4*>(h0n + 8 * q);
                float4 vb = *reinterpret_cast<const float4*>(h0n + 8 * q + 4);
                float4 wa = *reinterpret_cast<const float4*>(h1p + 8 * q);
                float4 wb = *reinterpret_cast<const float4*>(h1p + 8 * q + 4);
                aA0 = fmaf(va.x, wi1[8*q+0], aA0); aA0 = fmaf(va.y, wi1[8*q+1], aA0);
                aA0 = fmaf(va.z, wi1[8*q+2], aA0); aA0 = fmaf(va.w, wi1[8*q+3], aA0);
                aA1 = fmaf(vb.x, wi1[8*q+4], aA1); aA1 = fmaf(vb.y, wi1[8*q+5], aA1);
                aA1 = fmaf(vb.z, wi1[8*q+6], aA1); aA1 = fmaf(vb.w, wi1[8*q+7], aA1);
                aB0 = fmaf(wa.x, wh1[8*q+0], aB0); aB0 = fmaf(wa.y, wh1[8*q+1], aB0);
                aB0 = fmaf(wa.z, wh1[8*q+2], aB0); aB0 = fmaf(wa.w, wh1[8*q+3], aB0);
                aB1 = fmaf(wb.x, wh1[8*q+4], aB1); aB1 = fmaf(wb.y, wh1[8*q+5], aB1);
                aB1 = fmaf(wb.z, wh1[8*q+6], aB1); aB1 = fmaf(wb.w, wh1[8*q+7], aB1);
            }
            float2 t0 = *reinterpret_cast<const float2*>(h0n + 24);
            float2 t1 = *reinterpret_cast<const float2*>(h1p + 24);
            aA0 = fmaf(t0.x, wi1[24], aA0);
            aA1 = fmaf(t0.y, wi1[25], aA1);
            aB0 = fmaf(t1.x, wh1[24], aB0);
            aB1 = fmaf(t1.y, wh1[25], aB1);
            float acc = (aA0 + aA1) + (aB0 + aB1);
            acc += __shfl_xor(acc, 4, 64);
            float act = fmaf(am, sigm(am * acc), ad);
            float x1 = __shfl_xor(act, 1, 64);
            float x2 = __shfl_xor(act, 2, 64);
            float x3 = __shfl_xor(act, 3, 64);
            float gi = (r==0)?act : (r==1)?x1  : (r==2)?x2  : x3;
            float gf = (r==0)?x1  : (r==1)?act : (r==2)?x3  : x2;
            float gg = (r==0)?x2  : (r==1)?x3  : (r==2)?act : x1;
            float go = (r==0)?x3  : (r==1)?x2  : (r==2)?x1  : act;
            c1 = fmaf(gf, c1, gi * gg);
            float th = fmaf(2.f, sigm(2.f * c1), -1.f);
            float h1v = go * th;
            if ((tid & 7) == 0) H1[1 - p][slotj] = h1v;
            part = h1v * wlinj;                    // nonzero only at tid%8==0, j<51
        }
        // wave-level reduce of projection partials (stride-8 butterfly)
        part += __shfl_xor(part, 8, 64);
        part += __shfl_xor(part, 16, 64);
        part += __shfl_xor(part, 32, 64);
        if ((tid & 63) == 0) WS[tid >> 6] = part;
        __syncthreads();   // #2: h1(t) + wave partials visible

        if (tid < 8) {
            float s = WS[tid];          // WS[7] stays 0
            s += __shfl_xor(s, 1, 64);
            s += __shfl_xor(s, 2, 64);
            s += __shfl_xor(s, 4, 64);
            if (tid == 0) orow[t] = s + blin;
        }
    }
}

extern "C" void kernel_launch(void* const* d_in, const int* in_sizes, int n_in,
                              void* d_out, int out_size, void* d_ws, size_t ws_size,
                              hipStream_t stream) {
    const float* x     = (const float*)d_in[0];
    const float* W_ih0 = (const float*)d_in[1];
    const float* W_hh0 = (const float*)d_in[2];
    const float* b_ih0 = (const float*)d_in[3];
    const float* b_hh0 = (const float*)d_in[4];
    const float* W_ih1 = (const float*)d_in[5];
    const float* W_hh1 = (const float*)d_in[6];
    const float* b_ih1 = (const float*)d_in[7];
    const float* b_hh1 = (const float*)d_in[8];
    const float* W_lin = (const float*)d_in[9];
    const float* b_lin = (const float*)d_in[10];
    float* out = (float*)d_out;

    const int B = in_sizes[0] / TLEN;
    lstm2_kernel<<<dim3(B), dim3(NTH), 0, stream>>>(
        x, W_ih0, W_hh0, b_ih0, b_hh0, W_ih1, W_hh1, b_ih1, b_hh1, W_lin, b_lin, out);
}

// Round 5
// 2073.241 us; speedup vs baseline: 15.8809x; 1.4590x over previous
//
#include <hip/hip_runtime.h>

#define HID 51
#define TLEN 1024
#define NBATCH 4

typedef __attribute__((ext_vector_type(8))) short bf16x8;
typedef __attribute__((ext_vector_type(4))) float f32x4;

__device__ __forceinline__ float frcp(float v){ return __builtin_amdgcn_rcpf(v); }
__device__ __forceinline__ float sigm(float v){ return frcp(1.0f + __expf(-v)); }
__device__ __forceinline__ float tanh_f(float v){ return fmaf(2.f, sigm(2.f*v), -1.f); }
__device__ __forceinline__ unsigned short f2bf(float f){
    unsigned u = __float_as_uint(f);
    return (unsigned short)((u + 0x7FFFu + ((u>>16)&1u)) >> 16);   // RNE f32->bf16
}
__device__ __forceinline__ float bf2f(unsigned short b){ return __uint_as_float(((unsigned)b)<<16); }

// LDS h layout = MFMA B-fragment-linear: for k-tile kb (32 k's), lane l reads
// 8 consecutive-k bf16 (16B) at short-index kb*512 + l*8, covering
// k = 32*kb + 8*(l>>4) + 0..7, n = l&15.
// Writer (unit j, col n): short-index = (j>>5)*512 + (n + ((j>>3)&3)*16)*8 + (j&7).

__global__ __launch_bounds__(256, 1)
void lstm2_mfma(const float* __restrict__ x,
                const float* __restrict__ W_ih0, const float* __restrict__ W_hh0,
                const float* __restrict__ b_ih0, const float* __restrict__ b_hh0,
                const float* __restrict__ W_ih1, const float* __restrict__ W_hh1,
                const float* __restrict__ b_ih1, const float* __restrict__ b_hh1,
                const float* __restrict__ W_lin, const float* __restrict__ b_lin,
                float* __restrict__ out)
{
    const int tid = threadIdx.x;
    const int w = tid >> 6;          // wave 0..3
    const int l = tid & 63;          // lane
    const int n = l & 15;            // batch col (0..3 real) / A-row slot
    const int p = l >> 4;            // lane group 0..3

    __shared__ short H0hi[2][1024], H0lo[2][1024];
    __shared__ short H1hi[2][1024], H1lo[2][1024];
    __shared__ __align__(16) float PS[16][4];

    for (int i = tid; i < 1024; i += 256){
        H0hi[0][i]=0; H0hi[1][i]=0; H0lo[0][i]=0; H0lo[1][i]=0;
        H1hi[0][i]=0; H1hi[1][i]=0; H1lo[0][i]=0; H1lo[1][i]=0;
    }

    // ---- persistent weight fragments & epilogue constants ----
    bf16x8 Ahi0[4][2], Alo0[4][2], Ahi1[4][4], Alo1[4][4];
    f32x4 bias0v[4], bias1v[4], wih0v[4];
    float wlinv[4];
    int   widx4[4];

    #pragma unroll
    for (int tt=0; tt<4; ++tt){
        const int m = 4*tt + w;               // M-tile id
        const bool tv = (m < 13);
        // A-fragment: row = 16m + (l&15)  (gate-row order g = 4j + r)
        const int ar = 16*m + n;
        const int aj = ar >> 2, arr = ar & 3;
        const bool rowv = tv && (aj < HID);
        const int orow = arr*HID + aj;        // row in original [204] layout
        #pragma unroll
        for (int kb=0; kb<2; ++kb){
            bf16x8 hi, lo;
            #pragma unroll
            for (int jj=0; jj<8; ++jj){
                const int k = kb*32 + 8*p + jj;
                const float wv = (rowv && k < HID) ? W_hh0[orow*HID + k] : 0.f;
                const unsigned short hb = f2bf(wv);
                hi[jj] = (short)hb;
                lo[jj] = (short)f2bf(wv - bf2f(hb));
            }
            Ahi0[tt][kb] = hi; Alo0[tt][kb] = lo;
        }
        #pragma unroll
        for (int kb=0; kb<4; ++kb){
            bf16x8 hi, lo;
            #pragma unroll
            for (int jj=0; jj<8; ++jj){
                const int k = kb*32 + 8*p + jj;   // 0..127: [h0 (64) ; h1 (64)]
                float wv = 0.f;
                if (rowv){
                    if (k < 64) { if (k < HID) wv = W_ih1[orow*HID + k]; }
                    else        { const int kk = k - 64; if (kk < HID) wv = W_hh1[orow*HID + kk]; }
                }
                const unsigned short hb = f2bf(wv);
                hi[jj] = (short)hb;
                lo[jj] = (short)f2bf(wv - bf2f(hb));
            }
            Ahi1[tt][kb] = hi; Alo1[tt][kb] = lo;
        }
        // epilogue constants: this lane owns unit je = 4m+p (all 4 gates in acc regs)
        const int je = 4*m + p;
        const bool jev = tv && (je < HID);
        f32x4 b0, b1, wx;
        #pragma unroll
        for (int r4=0; r4<4; ++r4){
            const int oe = r4*HID + je;
            b0[r4] = jev ? b_ih0[oe] + b_hh0[oe] : 0.f;
            b1[r4] = jev ? b_ih1[oe] + b_hh1[oe] : 0.f;
            wx[r4] = jev ? W_ih0[oe] : 0.f;
        }
        bias0v[tt]=b0; bias1v[tt]=b1; wih0v[tt]=wx;
        wlinv[tt] = jev ? W_lin[je] : 0.f;
        widx4[tt] = ((je>>5)<<9) + (n + ((je>>3)&3)*16)*8 + (je&7);
    }

    const long long bb = (long long)blockIdx.x * NBATCH;
    const float* xr = x + (bb + (n < NBATCH ? n : NBATCH-1)) * TLEN;
    float xv = xr[0];
    float c0a[4] = {0.f,0.f,0.f,0.f};
    float c1a[4] = {0.f,0.f,0.f,0.f};
    const float blin = b_lin[0];

    __syncthreads();

    for (int t = 0; t < TLEN; ++t){
        const int cur = t & 1, prv = cur ^ 1;
        const float xnx = xr[(t+1 < TLEN) ? t+1 : TLEN-1];

        // ================= Layer 0 =================
        bf16x8 bh[2], bl[2];
        #pragma unroll
        for (int kb=0; kb<2; ++kb){
            bh[kb] = *reinterpret_cast<const bf16x8*>(&H0hi[prv][kb*512 + l*8]);
            bl[kb] = *reinterpret_cast<const bf16x8*>(&H0lo[prv][kb*512 + l*8]);
        }
        #pragma unroll
        for (int tt=0; tt<4; ++tt){
            const int m = 4*tt + w;
            if (m < 13){
                f32x4 acc = bias0v[tt];
                #pragma unroll
                for (int r4=0; r4<4; ++r4) acc[r4] = fmaf(xv, wih0v[tt][r4], acc[r4]);
                #pragma unroll
                for (int kb=0; kb<2; ++kb){
                    acc = __builtin_amdgcn_mfma_f32_16x16x32_bf16(Ahi0[tt][kb], bh[kb], acc, 0,0,0);
                    acc = __builtin_amdgcn_mfma_f32_16x16x32_bf16(Ahi0[tt][kb], bl[kb], acc, 0,0,0);
                    acc = __builtin_amdgcn_mfma_f32_16x16x32_bf16(Alo0[tt][kb], bh[kb], acc, 0,0,0);
                }
                const float gi = sigm(acc[0]);
                const float gf = sigm(acc[1]);
                const float gg = tanh_f(acc[2]);
                const float go = sigm(acc[3]);
                c0a[tt] = fmaf(gf, c0a[tt], gi*gg);
                const float hv = go * tanh_f(c0a[tt]);
                const unsigned short hh = f2bf(hv);
                const unsigned short hl = f2bf(hv - bf2f(hh));
                H0hi[cur][widx4[tt]] = (short)hh;
                H0lo[cur][widx4[tt]] = (short)hl;
            }
        }
        __syncthreads();   // h0(t) fragments visible

        // ================= Layer 1 + projection =================
        bf16x8 ch[4], cl[4];
        #pragma unroll
        for (int kb=0; kb<2; ++kb){
            ch[kb]   = *reinterpret_cast<const bf16x8*>(&H0hi[cur][kb*512 + l*8]);
            cl[kb]   = *reinterpret_cast<const bf16x8*>(&H0lo[cur][kb*512 + l*8]);
            ch[2+kb] = *reinterpret_cast<const bf16x8*>(&H1hi[prv][kb*512 + l*8]);
            cl[2+kb] = *reinterpret_cast<const bf16x8*>(&H1lo[prv][kb*512 + l*8]);
        }
        float ph = 0.f;
        #pragma unroll
        for (int tt=0; tt<4; ++tt){
            const int m = 4*tt + w;
            if (m < 13){
                f32x4 acc = bias1v[tt];
                #pragma unroll
                for (int kb=0; kb<4; ++kb){
                    acc = __builtin_amdgcn_mfma_f32_16x16x32_bf16(Ahi1[tt][kb], ch[kb], acc, 0,0,0);
                    acc = __builtin_amdgcn_mfma_f32_16x16x32_bf16(Ahi1[tt][kb], cl[kb], acc, 0,0,0);
                    acc = __builtin_amdgcn_mfma_f32_16x16x32_bf16(Alo1[tt][kb], ch[kb], acc, 0,0,0);
                }
                const float gi = sigm(acc[0]);
                const float gf = sigm(acc[1]);
                const float gg = tanh_f(acc[2]);
                const float go = sigm(acc[3]);
                c1a[tt] = fmaf(gf, c1a[tt], gi*gg);
                const float hv = go * tanh_f(c1a[tt]);
                const unsigned short hh = f2bf(hv);
                const unsigned short hl = f2bf(hv - bf2f(hh));
                H1hi[cur][widx4[tt]] = (short)hh;
                H1lo[cur][widx4[tt]] = (short)hl;
                ph = fmaf(hv, wlinv[tt], ph);
            }
        }
        // projection: sum over lane groups p (units) -> full wave sum per col n
        ph += __shfl_xor(ph, 16, 64);
        ph += __shfl_xor(ph, 32, 64);
        if (l < 16) PS[l][w] = ph;
        __syncthreads();   // h1(t) + wave partials visible

        if (w == 0 && l < 16){
            const float4 pp = *reinterpret_cast<const float4*>(&PS[l][0]);
            const float s = pp.x + pp.y + pp.z + pp.w + blin;
            if (l < NBATCH) out[(bb + l)*TLEN + t] = s;
        }
        xv = xnx;
    }
}

extern "C" void kernel_launch(void* const* d_in, const int* in_sizes, int n_in,
                              void* d_out, int out_size, void* d_ws, size_t ws_size,
                              hipStream_t stream) {
    const float* x     = (const float*)d_in[0];
    const float* W_ih0 = (const float*)d_in[1];
    const float* W_hh0 = (const float*)d_in[2];
    const float* b_ih0 = (const float*)d_in[3];
    const float* b_hh0 = (const float*)d_in[4];
    const float* W_ih1 = (const float*)d_in[5];
    const float* W_hh1 = (const float*)d_in[6];
    const float* b_ih1 = (const float*)d_in[7];
    const float* b_hh1 = (const float*)d_in[8];
    const float* W_lin = (const float*)d_in[9];
    const float* b_lin = (const float*)d_in[10];
    float* out = (float*)d_out;

    const int B = in_sizes[0] / TLEN;
    lstm2_mfma<<<dim3(B / NBATCH), dim3(256), 0, stream>>>(
        x, W_ih0, W_hh0, b_ih0, b_hh0, W_ih1, W_hh1, b_ih1, b_hh1, W_lin, b_lin, out);
}

// Round 6
// 2044.622 us; speedup vs baseline: 16.1032x; 1.0140x over previous
//
#include <hip/hip_runtime.h>

#define HID 51
#define TLEN 1024
#define NBATCH 4

typedef __attribute__((ext_vector_type(8))) short bf16x8;
typedef __attribute__((ext_vector_type(4))) float f32x4;

__device__ __forceinline__ float frcp(float v){ return __builtin_amdgcn_rcpf(v); }
__device__ __forceinline__ float sigm(float v){ return frcp(1.0f + __expf(-v)); }
__device__ __forceinline__ float tanh_f(float v){ return fmaf(2.f, sigm(2.f*v), -1.f); }
__device__ __forceinline__ unsigned short f2bf(float f){
    unsigned u = __float_as_uint(f);
    return (unsigned short)((u + 0x7FFFu + ((u>>16)&1u)) >> 16);   // RNE f32->bf16
}
__device__ __forceinline__ float bf2f(unsigned short b){ return __uint_as_float(((unsigned)b)<<16); }

// LDS h layout = MFMA B-fragment-linear (validated R4): lane l reads 16B at
// short-index kb*512 + l*8 covering k = 32*kb + 8*(l>>4) + 0..7, n = l&15.
// Writer (unit j, col n): short-index = (j>>5)*512 + (n + ((j>>3)&3)*16)*8 + (j&7).

__global__ __launch_bounds__(256, 1)
void lstm2_mfma(const float* __restrict__ x,
                const float* __restrict__ W_ih0, const float* __restrict__ W_hh0,
                const float* __restrict__ b_ih0, const float* __restrict__ b_hh0,
                const float* __restrict__ W_ih1, const float* __restrict__ W_hh1,
                const float* __restrict__ b_ih1, const float* __restrict__ b_hh1,
                const float* __restrict__ W_lin, const float* __restrict__ b_lin,
                float* __restrict__ out)
{
    const int tid = threadIdx.x;
    const int w = tid >> 6;          // wave 0..3
    const int l = tid & 63;          // lane
    const int n = l & 15;            // batch col / A-row slot
    const int p = l >> 4;            // lane group 0..3

    __shared__ short H0hi[2][1024], H0lo[2][1024];
    __shared__ short H1hi[2][1024], H1lo[2][1024];
    __shared__ __align__(16) float PS[2][16][4];

    for (int i = tid; i < 1024; i += 256){
        H0hi[0][i]=0; H0hi[1][i]=0; H0lo[0][i]=0; H0lo[1][i]=0;
        H1hi[0][i]=0; H1hi[1][i]=0; H1lo[0][i]=0; H1lo[1][i]=0;
    }
    if (tid < 128) (&PS[0][0][0])[tid] = 0.f;

    // ---- persistent weight fragments & epilogue constants (as R4) ----
    bf16x8 Ahi0[4][2], Alo0[4][2], Ahi1[4][4], Alo1[4][4];
    f32x4 bias0v[4], bias1v[4], wih0v[4];
    float wlinv[4];
    int   widx4[4];

    #pragma unroll
    for (int tt=0; tt<4; ++tt){
        const int m = 4*tt + w;               // M-tile id
        const bool tv = (m < 13);
        const int ar = 16*m + n;              // A-row = gate g = 4j + r
        const int aj = ar >> 2, arr = ar & 3;
        const bool rowv = tv && (aj < HID);
        const int orow = arr*HID + aj;
        #pragma unroll
        for (int kb=0; kb<2; ++kb){
            bf16x8 hi, lo;
            #pragma unroll
            for (int jj=0; jj<8; ++jj){
                const int k = kb*32 + 8*p + jj;
                const float wv = (rowv && k < HID) ? W_hh0[orow*HID + k] : 0.f;
                const unsigned short hb = f2bf(wv);
                hi[jj] = (short)hb;
                lo[jj] = (short)f2bf(wv - bf2f(hb));
            }
            Ahi0[tt][kb] = hi; Alo0[tt][kb] = lo;
        }
        #pragma unroll
        for (int kb=0; kb<4; ++kb){
            bf16x8 hi, lo;
            #pragma unroll
            for (int jj=0; jj<8; ++jj){
                const int k = kb*32 + 8*p + jj;   // 0..127: [h0 (64) ; h1 (64)]
                float wv = 0.f;
                if (rowv){
                    if (k < 64) { if (k < HID) wv = W_ih1[orow*HID + k]; }
                    else        { const int kk = k - 64; if (kk < HID) wv = W_hh1[orow*HID + kk]; }
                }
                const unsigned short hb = f2bf(wv);
                hi[jj] = (short)hb;
                lo[jj] = (short)f2bf(wv - bf2f(hb));
            }
            Ahi1[tt][kb] = hi; Alo1[tt][kb] = lo;
        }
        const int je = 4*m + p;               // unit this lane owns in epilogue
        const bool jev = tv && (je < HID);
        f32x4 b0, b1, wx;
        #pragma unroll
        for (int r4=0; r4<4; ++r4){
            const int oe = r4*HID + je;
            b0[r4] = jev ? b_ih0[oe] + b_hh0[oe] : 0.f;
            b1[r4] = jev ? b_ih1[oe] + b_hh1[oe] : 0.f;
            wx[r4] = jev ? W_ih0[oe] : 0.f;
        }
        bias0v[tt]=b0; bias1v[tt]=b1; wih0v[tt]=wx;
        wlinv[tt] = jev ? W_lin[je] : 0.f;
        widx4[tt] = ((je>>5)<<9) + (n + ((je>>3)&3)*16)*8 + (je&7);
    }

    const long long bb = (long long)blockIdx.x * NBATCH;
    const float* xr = x + (bb + (n < NBATCH ? n : NBATCH-1)) * TLEN;
    float xv = xr[0];
    float c0a[4] = {0.f,0.f,0.f,0.f};
    float c1a[4] = {0.f,0.f,0.f,0.f};
    const float blin = b_lin[0];

    __syncthreads();

    // Pipelined loop: iteration s does layer0(s) || layer1(s-1) || out(s-2),
    // ONE barrier per iteration. h0(t) lives in H0[t&1], h1(t) in H1[t&1].
    for (int s = 0; s <= TLEN; ++s){
        const int pw = s & 1, pr = pw ^ 1;
        const float xnx = xr[(s+1 < TLEN) ? s+1 : TLEN-1];

        // fragment reads: h0(s-1) (shared by both layers) and h1(s-2)
        bf16x8 r0h[2], r0l[2], r1h[2], r1l[2];
        #pragma unroll
        for (int kb=0; kb<2; ++kb){
            r0h[kb] = *reinterpret_cast<const bf16x8*>(&H0hi[pr][kb*512 + l*8]);
            r0l[kb] = *reinterpret_cast<const bf16x8*>(&H0lo[pr][kb*512 + l*8]);
            r1h[kb] = *reinterpret_cast<const bf16x8*>(&H1hi[pw][kb*512 + l*8]);
            r1l[kb] = *reinterpret_cast<const bf16x8*>(&H1lo[pw][kb*512 + l*8]);
        }

        // out(s-2): wave 3 (has only 3 M-tiles) sums PS written at iter s-1
        if (s >= 2 && w == 3 && l < NBATCH){
            const float4 pp = *reinterpret_cast<const float4*>(&PS[pr][l][0]);
            out[(bb + l)*TLEN + (s-2)] = pp.x + pp.y + pp.z + pp.w + blin;
        }

        // ---------------- layer 0, step s ----------------
        if (s < TLEN){
            #pragma unroll
            for (int tt=0; tt<4; ++tt){
                const int m = 4*tt + w;
                if (m < 13){
                    f32x4 a0 = bias0v[tt];
                    #pragma unroll
                    for (int r4=0; r4<4; ++r4) a0[r4] = fmaf(xv, wih0v[tt][r4], a0[r4]);
                    f32x4 a1 = {0.f,0.f,0.f,0.f}, a2 = {0.f,0.f,0.f,0.f};
                    #pragma unroll
                    for (int kb=0; kb<2; ++kb){
                        a0 = __builtin_amdgcn_mfma_f32_16x16x32_bf16(Ahi0[tt][kb], r0h[kb], a0, 0,0,0);
                        a1 = __builtin_amdgcn_mfma_f32_16x16x32_bf16(Ahi0[tt][kb], r0l[kb], a1, 0,0,0);
                        a2 = __builtin_amdgcn_mfma_f32_16x16x32_bf16(Alo0[tt][kb], r0h[kb], a2, 0,0,0);
                    }
                    const f32x4 pre = (a0 + a1) + a2;
                    const float gi = sigm(pre[0]);
                    const float gf = sigm(pre[1]);
                    const float gg = tanh_f(pre[2]);
                    const float go = sigm(pre[3]);
                    c0a[tt] = fmaf(gf, c0a[tt], gi*gg);
                    const float hv = go * tanh_f(c0a[tt]);
                    const unsigned short hh = f2bf(hv);
                    H0hi[pw][widx4[tt]] = (short)hh;
                    H0lo[pw][widx4[tt]] = (short)f2bf(hv - bf2f(hh));
                }
            }
        }

        // ---------------- layer 1, step s-1 + projection ----------------
        if (s >= 1){
            float ph = 0.f;
            #pragma unroll
            for (int tt=0; tt<4; ++tt){
                const int m = 4*tt + w;
                if (m < 13){
                    f32x4 b0 = bias1v[tt];
                    f32x4 b1 = {0.f,0.f,0.f,0.f}, b2 = {0.f,0.f,0.f,0.f};
                    #pragma unroll
                    for (int kb=0; kb<2; ++kb){
                        b0 = __builtin_amdgcn_mfma_f32_16x16x32_bf16(Ahi1[tt][kb],   r0h[kb], b0, 0,0,0);
                        b1 = __builtin_amdgcn_mfma_f32_16x16x32_bf16(Ahi1[tt][kb],   r0l[kb], b1, 0,0,0);
                        b2 = __builtin_amdgcn_mfma_f32_16x16x32_bf16(Alo1[tt][kb],   r0h[kb], b2, 0,0,0);
                        b0 = __builtin_amdgcn_mfma_f32_16x16x32_bf16(Ahi1[tt][kb+2], r1h[kb], b0, 0,0,0);
                        b1 = __builtin_amdgcn_mfma_f32_16x16x32_bf16(Ahi1[tt][kb+2], r1l[kb], b1, 0,0,0);
                        b2 = __builtin_amdgcn_mfma_f32_16x16x32_bf16(Alo1[tt][kb+2], r1h[kb], b2, 0,0,0);
                    }
                    const f32x4 pre = (b0 + b1) + b2;
                    const float gi = sigm(pre[0]);
                    const float gf = sigm(pre[1]);
                    const float gg = tanh_f(pre[2]);
                    const float go = sigm(pre[3]);
                    c1a[tt] = fmaf(gf, c1a[tt], gi*gg);
                    const float hv = go * tanh_f(c1a[tt]);
                    const unsigned short hh = f2bf(hv);
                    H1hi[pr][widx4[tt]] = (short)hh;
                    H1lo[pr][widx4[tt]] = (short)f2bf(hv - bf2f(hh));
                    ph = fmaf(hv, wlinv[tt], ph);
                }
            }
            ph += __shfl_xor(ph, 16, 64);
            ph += __shfl_xor(ph, 32, 64);
            if (l < 16) PS[pw][l][w] = ph;
        }

        __syncthreads();
        xv = xnx;
    }

    // tail: out(1023) from PS written at s=1024 (parity 0)
    if (w == 3 && l < NBATCH){
        const float4 pp = *reinterpret_cast<const float4*>(&PS[0][l][0]);
        out[(bb + l)*TLEN + (TLEN-1)] = pp.x + pp.y + pp.z + pp.w + blin;
    }
}

extern "C" void kernel_launch(void* const* d_in, const int* in_sizes, int n_in,
                              void* d_out, int out_size, void* d_ws, size_t ws_size,
                              hipStream_t stream) {
    const float* x     = (const float*)d_in[0];
    const float* W_ih0 = (const float*)d_in[1];
    const float* W_hh0 = (const float*)d_in[2];
    const float* b_ih0 = (const float*)d_in[3];
    const float* b_hh0 = (const float*)d_in[4];
    const float* W_ih1 = (const float*)d_in[5];
    const float* W_hh1 = (const float*)d_in[6];
    const float* b_ih1 = (const float*)d_in[7];
    const float* b_hh1 = (const float*)d_in[8];
    const float* W_lin = (const float*)d_in[9];
    const float* b_lin = (const float*)d_in[10];
    float* out = (float*)d_out;

    const int B = in_sizes[0] / TLEN;
    lstm2_mfma<<<dim3(B / NBATCH), dim3(256), 0, stream>>>(
        x, W_ih0, W_hh0, b_ih0, b_hh0, W_ih1, W_hh1, b_ih1, b_hh1, W_lin, b_lin, out);
}

// Round 7
// 1399.769 us; speedup vs baseline: 23.5217x; 1.4607x over previous
//
#include <hip/hip_runtime.h>

#define HID 51
#define TLEN 1024
#define NBATCH 4
#define NW 8              // waves per block
#define NTH (NW * 64)

typedef __attribute__((ext_vector_type(8))) short bf16x8;
typedef __attribute__((ext_vector_type(4))) float f32x4;

#define LOG2E 1.4426950408889634f

__device__ __forceinline__ float frcp(float v){ return __builtin_amdgcn_rcpf(v); }
// input already scaled by log2e (or 2*log2e for tanh-gate)
__device__ __forceinline__ float sigm2(float v){ return frcp(1.f + __builtin_amdgcn_exp2f(-v)); }
__device__ __forceinline__ float tanh_c(float c){   // c in true domain
    return fmaf(2.f, frcp(1.f + __builtin_amdgcn_exp2f(-2.f*LOG2E*c)), -1.f);
}
__device__ __forceinline__ unsigned short f2bf(float f){
    unsigned u = __float_as_uint(f);
    return (unsigned short)((u + 0x7FFFu + ((u>>16)&1u)) >> 16);   // RNE f32->bf16
}
__device__ __forceinline__ float bf2f(unsigned short b){ return __uint_as_float(((unsigned)b)<<16); }

// LDS h layout = MFMA B-fragment-linear (validated R4): lane l reads 16B at
// short-index kb*512 + l*8 covering k = 32*kb + 8*(l>>4) + 0..7, n = l&15.
// Writer (unit j, col n): short-index = (j>>5)*512 + (n + ((j>>3)&3)*16)*8 + (j&7).

__global__ __launch_bounds__(NTH, 2)
void lstm2_mfma(const float* __restrict__ x,
                const float* __restrict__ W_ih0, const float* __restrict__ W_hh0,
                const float* __restrict__ b_ih0, const float* __restrict__ b_hh0,
                const float* __restrict__ W_ih1, const float* __restrict__ W_hh1,
                const float* __restrict__ b_ih1, const float* __restrict__ b_hh1,
                const float* __restrict__ W_lin, const float* __restrict__ b_lin,
                float* __restrict__ out)
{
    const int tid = threadIdx.x;
    const int w = tid >> 6;          // wave 0..7
    const int l = tid & 63;          // lane
    const int n = l & 15;            // batch col / A-row slot
    const int p = l >> 4;            // lane group 0..3

    __shared__ short H0hi[2][1024], H0lo[2][1024];
    __shared__ short H1hi[2][1024], H1lo[2][1024];
    __shared__ __align__(16) float PS[2][16][NW];

    for (int i = tid; i < 1024; i += NTH){
        H0hi[0][i]=0; H0hi[1][i]=0; H0lo[0][i]=0; H0lo[1][i]=0;
        H1hi[0][i]=0; H1hi[1][i]=0; H1lo[0][i]=0; H1lo[1][i]=0;
    }
    if (tid < 2*16*NW) (&PS[0][0][0])[tid] = 0.f;

    // ---- persistent weight fragments & epilogue constants ----
    // wave w owns M-tiles m = w + 8*tt, tt in {0,1}; valid iff m < 13.
    bf16x8 Ahi0[2][2], Alo0[2][2], Ahi1[2][4], Alo1[2][4];
    f32x4 bias0v[2], bias1v[2], wih0v[2];
    float wlinv[2];
    int   widx4[2];

    #pragma unroll
    for (int tt=0; tt<2; ++tt){
        const int m = w + 8*tt;               // M-tile id
        const bool tv = (m < 13);
        const int ar = 16*m + n;              // A-row = gate g = 4j + r
        const int aj = ar >> 2, arr = ar & 3;
        const bool rowv = tv && (aj < HID);
        const int orow = arr*HID + aj;
        const float gsc = (arr == 2) ? 2.f*LOG2E : LOG2E;   // pre-scale into exp2 domain
        #pragma unroll
        for (int kb=0; kb<2; ++kb){
            bf16x8 hi, lo;
            #pragma unroll
            for (int jj=0; jj<8; ++jj){
                const int k = kb*32 + 8*p + jj;
                const float wv = (rowv && k < HID) ? gsc * W_hh0[orow*HID + k] : 0.f;
                const unsigned short hb = f2bf(wv);
                hi[jj] = (short)hb;
                lo[jj] = (short)f2bf(wv - bf2f(hb));
            }
            Ahi0[tt][kb] = hi; Alo0[tt][kb] = lo;
        }
        #pragma unroll
        for (int kb=0; kb<4; ++kb){
            bf16x8 hi, lo;
            #pragma unroll
            for (int jj=0; jj<8; ++jj){
                const int k = kb*32 + 8*p + jj;   // 0..127: [h0 (64) ; h1 (64)]
                float wv = 0.f;
                if (rowv){
                    if (k < 64) { if (k < HID) wv = W_ih1[orow*HID + k]; }
                    else        { const int kk = k - 64; if (kk < HID) wv = W_hh1[orow*HID + kk]; }
                }
                wv *= gsc;
                const unsigned short hb = f2bf(wv);
                hi[jj] = (short)hb;
                lo[jj] = (short)f2bf(wv - bf2f(hb));
            }
            Ahi1[tt][kb] = hi; Alo1[tt][kb] = lo;
        }
        const int je = 4*m + p;               // unit this lane owns in epilogue
        const bool jev = tv && (je < HID);
        f32x4 b0, b1, wx;
        #pragma unroll
        for (int r4=0; r4<4; ++r4){
            const float gs4 = (r4 == 2) ? 2.f*LOG2E : LOG2E;
            const int oe = r4*HID + je;
            b0[r4] = jev ? gs4 * (b_ih0[oe] + b_hh0[oe]) : 0.f;
            b1[r4] = jev ? gs4 * (b_ih1[oe] + b_hh1[oe]) : 0.f;
            wx[r4] = jev ? gs4 * W_ih0[oe] : 0.f;
        }
        bias0v[tt]=b0; bias1v[tt]=b1; wih0v[tt]=wx;
        wlinv[tt] = jev ? W_lin[je] : 0.f;
        widx4[tt] = ((je>>5)<<9) + (n + ((je>>3)&3)*16)*8 + (je&7);
    }

    const long long bb = (long long)blockIdx.x * NBATCH;
    const float* xr = x + (bb + (n < NBATCH ? n : NBATCH-1)) * TLEN;
    float xv = xr[0];
    float c0a[2] = {0.f,0.f};
    float c1a[2] = {0.f,0.f};
    const float blin = b_lin[0];

    __syncthreads();

    // Pipelined loop (R5 structure): iter s = layer0(s) || layer1(s-1) || out(s-2).
    for (int s = 0; s <= TLEN; ++s){
        const int pw = s & 1, pr = pw ^ 1;
        const float xnx = xr[(s+1 < TLEN) ? s+1 : TLEN-1];

        // fragment reads: h0(s-1) (shared by both layers) and h1(s-2)
        bf16x8 r0h[2], r0l[2], r1h[2], r1l[2];
        #pragma unroll
        for (int kb=0; kb<2; ++kb){
            r0h[kb] = *reinterpret_cast<const bf16x8*>(&H0hi[pr][kb*512 + l*8]);
            r0l[kb] = *reinterpret_cast<const bf16x8*>(&H0lo[pr][kb*512 + l*8]);
            r1h[kb] = *reinterpret_cast<const bf16x8*>(&H1hi[pw][kb*512 + l*8]);
            r1l[kb] = *reinterpret_cast<const bf16x8*>(&H1lo[pw][kb*512 + l*8]);
        }

        // out(s-2): wave 7 (single-tile wave) sums PS written at iter s-1
        if (s >= 2 && w == 7 && l < NBATCH){
            const float4 pa = *reinterpret_cast<const float4*>(&PS[pr][l][0]);
            const float4 pb = *reinterpret_cast<const float4*>(&PS[pr][l][4]);
            out[(bb + l)*TLEN + (s-2)] =
                ((pa.x + pa.y) + (pa.z + pa.w)) + ((pb.x + pb.y) + (pb.z + pb.w)) + blin;
        }

        // ---------------- layer 0, step s ----------------
        if (s < TLEN){
            #pragma unroll
            for (int tt=0; tt<2; ++tt){
                const int m = w + 8*tt;
                if (m < 13){
                    f32x4 a0 = bias0v[tt];
                    #pragma unroll
                    for (int r4=0; r4<4; ++r4) a0[r4] = fmaf(xv, wih0v[tt][r4], a0[r4]);
                    f32x4 a1 = {0.f,0.f,0.f,0.f}, a2 = {0.f,0.f,0.f,0.f};
                    #pragma unroll
                    for (int kb=0; kb<2; ++kb){
                        a0 = __builtin_amdgcn_mfma_f32_16x16x32_bf16(Ahi0[tt][kb], r0h[kb], a0, 0,0,0);
                        a1 = __builtin_amdgcn_mfma_f32_16x16x32_bf16(Ahi0[tt][kb], r0l[kb], a1, 0,0,0);
                        a2 = __builtin_amdgcn_mfma_f32_16x16x32_bf16(Alo0[tt][kb], r0h[kb], a2, 0,0,0);
                    }
                    const f32x4 pre = (a0 + a1) + a2;
                    const float gi = sigm2(pre[0]);
                    const float gf = sigm2(pre[1]);
                    const float gg = fmaf(2.f, sigm2(pre[2]), -1.f);   // tanh via 2*log2e prescale
                    const float go = sigm2(pre[3]);
                    c0a[tt] = fmaf(gf, c0a[tt], gi*gg);
                    const float hv = go * tanh_c(c0a[tt]);
                    const unsigned short hh = f2bf(hv);
                    H0hi[pw][widx4[tt]] = (short)hh;
                    H0lo[pw][widx4[tt]] = (short)f2bf(hv - bf2f(hh));
                }
            }
        }

        // ---------------- layer 1, step s-1 + projection ----------------
        if (s >= 1){
            float ph = 0.f;
            #pragma unroll
            for (int tt=0; tt<2; ++tt){
                const int m = w + 8*tt;
                if (m < 13){
                    f32x4 b0 = bias1v[tt];
                    f32x4 b1 = {0.f,0.f,0.f,0.f}, b2 = {0.f,0.f,0.f,0.f};
                    #pragma unroll
                    for (int kb=0; kb<2; ++kb){
                        b0 = __builtin_amdgcn_mfma_f32_16x16x32_bf16(Ahi1[tt][kb],   r0h[kb], b0, 0,0,0);
                        b1 = __builtin_amdgcn_mfma_f32_16x16x32_bf16(Ahi1[tt][kb],   r0l[kb], b1, 0,0,0);
                        b2 = __builtin_amdgcn_mfma_f32_16x16x32_bf16(Alo1[tt][kb],   r0h[kb], b2, 0,0,0);
                        b0 = __builtin_amdgcn_mfma_f32_16x16x32_bf16(Ahi1[tt][kb+2], r1h[kb], b0, 0,0,0);
                        b1 = __builtin_amdgcn_mfma_f32_16x16x32_bf16(Ahi1[tt][kb+2], r1l[kb], b1, 0,0,0);
                        b2 = __builtin_amdgcn_mfma_f32_16x16x32_bf16(Alo1[tt][kb+2], r1h[kb], b2, 0,0,0);
                    }
                    const f32x4 pre = (b0 + b1) + b2;
                    const float gi = sigm2(pre[0]);
                    const float gf = sigm2(pre[1]);
                    const float gg = fmaf(2.f, sigm2(pre[2]), -1.f);
                    const float go = sigm2(pre[3]);
                    c1a[tt] = fmaf(gf, c1a[tt], gi*gg);
                    const float hv = go * tanh_c(c1a[tt]);
                    const unsigned short hh = f2bf(hv);
                    H1hi[pr][widx4[tt]] = (short)hh;
                    H1lo[pr][widx4[tt]] = (short)f2bf(hv - bf2f(hh));
                    ph = fmaf(hv, wlinv[tt], ph);
                }
            }
            ph += __shfl_xor(ph, 16, 64);
            ph += __shfl_xor(ph, 32, 64);
            if (l < 16) PS[pw][l][w] = ph;
        }

        __syncthreads();
        xv = xnx;
    }

    // tail: out(1023) from PS written at s=1024 (parity 0)
    if (w == 7 && l < NBATCH){
        const float4 pa = *reinterpret_cast<const float4*>(&PS[0][l][0]);
        const float4 pb = *reinterpret_cast<const float4*>(&PS[0][l][4]);
        out[(bb + l)*TLEN + (TLEN-1)] =
            ((pa.x + pa.y) + (pa.z + pa.w)) + ((pb.x + pb.y) + (pb.z + pb.w)) + blin;
    }
}

extern "C" void kernel_launch(void* const* d_in, const int* in_sizes, int n_in,
                              void* d_out, int out_size, void* d_ws, size_t ws_size,
                              hipStream_t stream) {
    const float* x     = (const float*)d_in[0];
    const float* W_ih0 = (const float*)d_in[1];
    const float* W_hh0 = (const float*)d_in[2];
    const float* b_ih0 = (const float*)d_in[3];
    const float* b_hh0 = (const float*)d_in[4];
    const float* W_ih1 = (const float*)d_in[5];
    const float* W_hh1 = (const float*)d_in[6];
    const float* b_ih1 = (const float*)d_in[7];
    const float* b_hh1 = (const float*)d_in[8];
    const float* W_lin = (const float*)d_in[9];
    const float* b_lin = (const float*)d_in[10];
    float* out = (float*)d_out;

    const int B = in_sizes[0] / TLEN;
    lstm2_mfma<<<dim3(B / NBATCH), dim3(NTH), 0, stream>>>(
        x, W_ih0, W_hh0, b_ih0, b_hh0, W_ih1, W_hh1, b_ih1, b_hh1, W_lin, b_lin, out);
}